// Round 16
// baseline (120.807 us; speedup 1.0000x reference)
//
#include <hip/hip_runtime.h>
#include <stdint.h>

#define Bn  8
#define LQn 2048
#define LKn 2048
#define Dn  512
#define NT  8           // 2048 keys / 256 per iter

using f32x4  = __attribute__((ext_vector_type(4)))  float;
using f32x16 = __attribute__((ext_vector_type(16))) float;
using bf16x8 = __attribute__((ext_vector_type(8)))  __bf16;
using u16x8  = __attribute__((ext_vector_type(8)))  unsigned short;

// ws layout
#define WS_MASK_OFF 256                                      // u32 bitmask: [B][64] (2 KiB)
#define WS_KP_OFF   (WS_MASK_OFF + Bn*LKn*4)                 // K pack: [B][64 kg][32 ks][64 lane][8] bf16
#define KP_BYTES    ((size_t)Bn*64*32*1024)
#define WS_VP_OFF   (WS_KP_OFF + KP_BYTES)                   // V pack: [B][128 kslice][16 dg][64 lane][8] bf16
#define VP_BYTES    ((size_t)Bn*128*16*1024)
#define WS_REQ      ((size_t)WS_VP_OFF + VP_BYTES)

union BFU { __bf16 h; unsigned short u; };
static __device__ __forceinline__ unsigned short f2bfu(float x) { BFU t; t.h = (__bf16)x; return t.u; }

// ---- mask dtype detect + bitmask build: bit=1 <=> masked ----
__global__ void mask_prep_kernel(const void* __restrict__ mraw, unsigned* __restrict__ mbits) {
  __shared__ int sBig, sOff;
  const int tid = threadIdx.x;
  if (tid == 0) { sBig = 0; sOff = 0; }
  __syncthreads();
  const unsigned char* mb = (const unsigned char*)mraw;
  int big = 0, off = 0;
  for (int i = tid; i < Bn*LKn; i += blockDim.x) {
    unsigned char v = mb[i];
    big |= (v > 1) ? 1 : 0;
    off |= (((i & 3) != 0) && v != 0) ? 1 : 0;
  }
  if (big) atomicOr(&sBig, 1);
  if (off) atomicOr(&sOff, 1);
  __syncthreads();
  const int f = sBig ? 2 : (sOff ? 1 : 0);
  unsigned v = 0;
#pragma unroll 1
  for (int j = 0; j < 32; ++j) {
    const int i = tid*32 + j;
    bool m;
    if (f == 2)      m = ((const float*)mraw)[i] != 0.0f;
    else if (f == 1) m = mb[i] != 0;
    else             m = ((const int*)mraw)[i] != 0;
    v |= (m ? 1u : 0u) << j;
  }
  mbits[tid] = v;
}

// ---- K fp32 [B][LK][D] -> Kp frag-packed bf16 ----
__global__ void conv_kp_kernel(const float* __restrict__ k, unsigned short* __restrict__ kp) {
  const int gid = blockIdx.x * 256 + threadIdx.x;
  const int frag = gid >> 6, lane = gid & 63;
  const int b = frag >> 11;
  const int rem = frag & 2047;
  const int kg = rem >> 5, ks = rem & 31;
  const int key = kg*32 + (lane & 31);
  const int hi = lane >> 5;
  const float* src = k + ((size_t)(b*LKn) + key)*Dn + ks*16 + hi*8;
  const f32x4 a = *(const f32x4*)src;
  const f32x4 c = *(const f32x4*)(src + 4);
  u16x8 o;
#pragma unroll
  for (int j = 0; j < 4; ++j) { o[j] = f2bfu(a[j]); o[j+4] = f2bfu(c[j]); }
  *(u16x8*)(kp + (size_t)frag*512 + lane*8) = o;
}

// ---- V fp32 [B][LK][D] -> Vp frag-packed bf16: [B][kslice][dg][lane][8] ----
__global__ void conv_vp_kernel(const float* __restrict__ v, unsigned short* __restrict__ vp) {
  __shared__ float vt[16*512];
  const int b = blockIdx.y, kslice = blockIdx.x;
  const float* src = v + ((size_t)(b*LKn) + kslice*16)*Dn;
#pragma unroll
  for (int p = 0; p < 8; ++p) {
    const int idx = p*256 + threadIdx.x;
    *(f32x4*)&vt[idx*4] = *(const f32x4*)(src + (size_t)idx*4);
  }
  __syncthreads();
  unsigned short* dst = vp + ((size_t)(b*128 + kslice)*16)*512;
#pragma unroll
  for (int p = 0; p < 4; ++p) {
    const int slot = p*256 + threadIdx.x;
    const int dg = slot >> 6, lane = slot & 63;
    const int d = dg*32 + (lane & 31);
    const int k0 = (lane >> 5)*8;
    u16x8 o;
#pragma unroll
    for (int j = 0; j < 8; ++j) o[j] = f2bfu(vt[(k0+j)*512 + d]);
    *(u16x8*)(dst + (size_t)dg*512 + lane*8) = o;
  }
}

#define BARRIER_LGKM                                        \
  asm volatile("s_waitcnt lgkmcnt(0)" ::: "memory");        \
  __builtin_amdgcn_s_barrier();                             \
  asm volatile("" ::: "memory");

// P buffer geometry (bytes): per-buffer stride 32768, qg stride 16384
#define PBUF 32768
#define PQG  16384

// ---- flash attention: QBLK=64, 8 waves x 32 keys/iter, fixed-base softmax (M=8) ----
// 32-slot unified ring (distance 32) + 2-step LDS read lookahead in QKT/PV.
__launch_bounds__(512, 2)
__global__ void attn_kernel(const float* __restrict__ q, const unsigned short* __restrict__ kp,
                            const unsigned short* __restrict__ vp,
                            const float* __restrict__ ratio, const float* __restrict__ scalep,
                            const unsigned* __restrict__ mbp, float* __restrict__ out) {
  __shared__ __align__(16) unsigned short Ql[2*32*512];     // 64 KiB: [qg][ks][hi][qc][8] bf16
  __shared__ __align__(16) unsigned short Pl[2][2*16*512];  // 64 KiB: dbuf x [qg][ks][hi][qc][8]
  __shared__ float redl[8][64];                             // epilogue l reduction

  const int tid = threadIdx.x;
  const int w = tid >> 6, lane = tid & 63;
  const int qc = lane & 31, hi = lane >> 5;
  const int b = blockIdx.x & 7, qtile = blockIdx.x >> 3;   // XCD-affine batches
  const int qbase = qtile * 64;
  const float c2 = scalep[0] * ratio[b] * 1.4426950408889634f;

  // stage Q -> LDS bf16 frag layout [qg][ks][hi][qc][16B]
#pragma unroll
  for (int cc = 0; cc < 8; ++cc) {
    const int idx = cc*512 + tid;
    const int hi2 = idx & 1, qc2 = (idx >> 1) & 31, ks2 = (idx >> 6) & 31, qg2 = idx >> 11;
    const float* src = q + ((size_t)(b*LQn) + qbase + qg2*32 + qc2)*Dn + ks2*16 + hi2*8;
    const f32x4 a = *(const f32x4*)src;
    const f32x4 bb = *(const f32x4*)(src + 4);
    u16x8 o;
#pragma unroll
    for (int j = 0; j < 4; ++j) { o[j] = f2bfu(a[j]); o[j+4] = f2bfu(bb[j]); }
    *(u16x8*)((char*)Ql + qg2*32768 + ks2*1024 + hi2*512 + qc2*16) = o;
  }
  __syncthreads();   // prologue-only full drain

  f32x16 o00, o01, o10, o11;
#pragma unroll
  for (int r = 0; r < 16; ++r) { o00[r]=0.f; o01[r]=0.f; o10[r]=0.f; o11[r]=0.f; }
  float lacc0 = 0.f, lacc1 = 0.f;

  const char* kpB = (const char*)kp + (size_t)b*2048*1024;
  const char* vpB = (const char*)vp + (size_t)b*2048*1024;
  const int loff = lane*16;
  const char* Qlb = (const char*)Ql + hi*512 + qc*16;     // conflict-free frag base
  const char* prc = (const char*)Pl + hi*512 + qc*16;

  // 32-slot unified ring: preload all K frags of iter 0
  bf16x8 pb[32];
  {
    const char* kf0 = kpB + (size_t)w*32768 + loff;
#pragma unroll
    for (int i = 0; i < 32; ++i) pb[i] = *(const bf16x8*)(kf0 + i*1024);
  }

  for (int t = 0; t < NT; ++t) {
    const char* vf  = vpB + ((size_t)(t*256) + w*2)*1024 + loff;
    const char* kfn = kpB + (size_t)(((t+1) & (NT-1))*8 + w)*32768 + loff;  // wraps at t=NT-1
    const unsigned mb32 = mbp[b*64 + t*8 + w];              // uniform -> s_load
    const unsigned mlane = mb32 >> (hi*4);                  // per-lane bit base

    // ---- QK^T: 2-step Q lookahead; step i consumes K[i], refills V[i] (distance 32) ----
    f32x16 S0, S1;
#pragma unroll
    for (int r = 0; r < 16; ++r) { S0[r] = 0.f; S1[r] = 0.f; }
    bf16x8 qa[2][2];
    qa[0][0] = *(const bf16x8*)(Qlb);
    qa[0][1] = *(const bf16x8*)(Qlb + 32768);
    qa[1][0] = *(const bf16x8*)(Qlb + 1024);
    qa[1][1] = *(const bf16x8*)(Qlb + 32768 + 1024);
    __builtin_amdgcn_s_setprio(1);
#pragma unroll
    for (int i = 0; i < 32; ++i) {
      const bf16x8 kk = pb[i];
      const bf16x8 q0 = qa[i & 1][0];
      const bf16x8 q1 = qa[i & 1][1];
      pb[i] = *(const bf16x8*)(vf + (size_t)(i >> 1)*16384 + (i & 1)*1024);   // V refill (early)
      if (i < 30) {
        qa[i & 1][0] = *(const bf16x8*)(Qlb + (i+2)*1024);
        qa[i & 1][1] = *(const bf16x8*)(Qlb + 32768 + (i+2)*1024);
      }
      S0 = __builtin_amdgcn_mfma_f32_32x32x16_bf16(kk, q0, S0, 0, 0, 0);
      S1 = __builtin_amdgcn_mfma_f32_32x32x16_bf16(kk, q1, S1, 0, 0, 0);
    }
    __builtin_amdgcn_s_setprio(0);

    // ---- fixed-base exp (p = masked ? 0 : exp2(S*c2 - 8)) + pack + partial l ----
    float ps0 = 0.f, ps1 = 0.f;
    {
      char* pwr = (char*)Pl + (t & 1)*PBUF + (w*2)*1024 + qc*16 + hi*8;
#pragma unroll
      for (int g = 0; g < 4; ++g) {
        const int off = (g >> 1)*1024 + (g & 1)*512;
        float p0 = ((mlane >> (8*g + 0)) & 1) ? 0.0f : exp2f(fmaf(S0[g*4+0], c2, -8.0f));
        float p1 = ((mlane >> (8*g + 1)) & 1) ? 0.0f : exp2f(fmaf(S0[g*4+1], c2, -8.0f));
        float p2 = ((mlane >> (8*g + 2)) & 1) ? 0.0f : exp2f(fmaf(S0[g*4+2], c2, -8.0f));
        float p3 = ((mlane >> (8*g + 3)) & 1) ? 0.0f : exp2f(fmaf(S0[g*4+3], c2, -8.0f));
        ps0 += (p0 + p1) + (p2 + p3);
        unsigned long long u0 = (unsigned long long)((unsigned int)f2bfu(p0) | ((unsigned int)f2bfu(p1) << 16))
                              | ((unsigned long long)((unsigned int)f2bfu(p2) | ((unsigned int)f2bfu(p3) << 16)) << 32);
        *(unsigned long long*)(pwr + off) = u0;
        p0 = ((mlane >> (8*g + 0)) & 1) ? 0.0f : exp2f(fmaf(S1[g*4+0], c2, -8.0f));
        p1 = ((mlane >> (8*g + 1)) & 1) ? 0.0f : exp2f(fmaf(S1[g*4+1], c2, -8.0f));
        p2 = ((mlane >> (8*g + 2)) & 1) ? 0.0f : exp2f(fmaf(S1[g*4+2], c2, -8.0f));
        p3 = ((mlane >> (8*g + 3)) & 1) ? 0.0f : exp2f(fmaf(S1[g*4+3], c2, -8.0f));
        ps1 += (p0 + p1) + (p2 + p3);
        unsigned long long u1 = (unsigned long long)((unsigned int)f2bfu(p0) | ((unsigned int)f2bfu(p1) << 16))
                              | ((unsigned long long)((unsigned int)f2bfu(p2) | ((unsigned int)f2bfu(p3) << 16)) << 32);
        *(unsigned long long*)(pwr + PQG + off) = u1;
      }
    }
    ps0 += __shfl_xor(ps0, 32);
    ps1 += __shfl_xor(ps1, 32);
    lacc0 += ps0;
    lacc1 += ps1;

    BARRIER_LGKM;   // single barrier: P(t) visible; prior PV reads of this buffer long done

    // ---- PV(t): 2-step P lookahead; step j consumes V[j], refills K_next[j] ----
    const char* prd = prc + (t & 1)*PBUF;
    bf16x8 pf[2][2];
    pf[0][0] = *(const bf16x8*)(prd);
    pf[0][1] = *(const bf16x8*)(prd + PQG);
    pf[1][0] = *(const bf16x8*)(prd + 1024);
    pf[1][1] = *(const bf16x8*)(prd + PQG + 1024);
    __builtin_amdgcn_s_setprio(1);
#pragma unroll
    for (int ks2 = 0; ks2 < 16; ++ks2) {
      const int j0 = 2*ks2, j1 = 2*ks2 + 1;
      const bf16x8 pf0 = pf[ks2 & 1][0];
      const bf16x8 pf1 = pf[ks2 & 1][1];
      const bf16x8 v0 = pb[j0];
      const bf16x8 v1 = pb[j1];
      pb[j0] = *(const bf16x8*)(kfn + j0*1024);             // K refill (early)
      pb[j1] = *(const bf16x8*)(kfn + j1*1024);
      if (ks2 < 14) {
        pf[ks2 & 1][0] = *(const bf16x8*)(prd + (ks2+2)*1024);
        pf[ks2 & 1][1] = *(const bf16x8*)(prd + PQG + (ks2+2)*1024);
      }
      o00 = __builtin_amdgcn_mfma_f32_32x32x16_bf16(v0, pf0, o00, 0, 0, 0);
      o10 = __builtin_amdgcn_mfma_f32_32x32x16_bf16(v0, pf1, o10, 0, 0, 0);
      o01 = __builtin_amdgcn_mfma_f32_32x32x16_bf16(v1, pf0, o01, 0, 0, 0);
      o11 = __builtin_amdgcn_mfma_f32_32x32x16_bf16(v1, pf1, o11, 0, 0, 0);
    }
    __builtin_amdgcn_s_setprio(0);
  }

  // ---- epilogue: cross-wave l reduction (once), then out = O^T / l ----
  if (lane < 32) { redl[w][qc] = lacc0; redl[w][32 + qc] = lacc1; }
  BARRIER_LGKM;
  float l0 = redl[0][qc], l1 = redl[0][32 + qc];
#pragma unroll
  for (int w2 = 1; w2 < 8; ++w2) { l0 += redl[w2][qc]; l1 += redl[w2][32 + qc]; }

  const float li0 = 1.0f / l0, li1 = 1.0f / l1;
  float* ob0 = out + ((size_t)(b*LQn) + qbase + qc)*Dn + w*64;
  float* ob1 = ob0 + (size_t)32*Dn;
#pragma unroll
  for (int dg = 0; dg < 2; ++dg) {
#pragma unroll
    for (int rq = 0; rq < 4; ++rq) {
      f32x4 ov0, ov1;
#pragma unroll
      for (int c = 0; c < 4; ++c) {
        if (dg == 0) { ov0[c] = o00[rq*4 + c]*li0; ov1[c] = o10[rq*4 + c]*li1; }
        else         { ov0[c] = o01[rq*4 + c]*li0; ov1[c] = o11[rq*4 + c]*li1; }
      }
      *(f32x4*)(ob0 + dg*32 + rq*8 + hi*4) = ov0;
      *(f32x4*)(ob1 + dg*32 + rq*8 + hi*4) = ov1;
    }
  }
}

extern "C" void kernel_launch(void* const* d_in, const int* in_sizes, int n_in,
                              void* d_out, int out_size, void* d_ws, size_t ws_size,
                              hipStream_t stream) {
  const float* q      = (const float*)d_in[0];
  const float* k      = (const float*)d_in[1];
  const float* v      = (const float*)d_in[2];
  const float* ratio  = (const float*)d_in[3];
  const float* scalep = (const float*)d_in[4];
  const void*  mask   = d_in[5];
  float* out = (float*)d_out;
  char* ws = (char*)d_ws;

  if (ws_size < WS_REQ) return;

  unsigned* mbits     = (unsigned*)(ws + WS_MASK_OFF);
  unsigned short* kpk = (unsigned short*)(ws + WS_KP_OFF);
  unsigned short* vpk = (unsigned short*)(ws + WS_VP_OFF);

  hipLaunchKernelGGL(mask_prep_kernel, dim3(1), dim3(512), 0, stream, mask, mbits);
  hipLaunchKernelGGL(conv_kp_kernel, dim3(Bn*64*32*64/256), dim3(256), 0, stream, k, kpk);
  hipLaunchKernelGGL(conv_vp_kernel, dim3(128, Bn), dim3(256), 0, stream, v, vpk);
  hipLaunchKernelGGL(attn_kernel, dim3(Bn*(LQn/64)), dim3(512), 0, stream,
                     q, kpk, vpk, ratio, scalep, mbits, out);
}

// Round 17
// 115.971 us; speedup vs baseline: 1.0417x; 1.0417x over previous
//
#include <hip/hip_runtime.h>
#include <stdint.h>

#define Bn  8
#define LQn 2048
#define LKn 2048
#define Dn  512
#define NT  8           // 2048 keys / 256 per iter

using f32x4  = __attribute__((ext_vector_type(4)))  float;
using f32x16 = __attribute__((ext_vector_type(16))) float;
using bf16x8 = __attribute__((ext_vector_type(8)))  __bf16;
using u16x8  = __attribute__((ext_vector_type(8)))  unsigned short;

// ws layout
#define WS_MASK_OFF 256                                      // u32 bitmask: [B][64] (2 KiB)
#define WS_KP_OFF   (WS_MASK_OFF + Bn*LKn*4)                 // K pack: [B][64 kg][32 ks][64 lane][8] bf16
#define KP_BYTES    ((size_t)Bn*64*32*1024)
#define WS_VP_OFF   (WS_KP_OFF + KP_BYTES)                   // V pack: [B][128 kslice][16 dg][64 lane][8] bf16
#define VP_BYTES    ((size_t)Bn*128*16*1024)
#define WS_REQ      ((size_t)WS_VP_OFF + VP_BYTES)

union BFU { __bf16 h; unsigned short u; };
static __device__ __forceinline__ unsigned short f2bfu(float x) { BFU t; t.h = (__bf16)x; return t.u; }

// ---- fused preprocessing: K-pack | V-pack | mask bitmask in ONE launch ----
// grid.x = 4096 (kp) + 1024 (vp) + 1 (mask), block = 256
__global__ void prep_kernel(const float* __restrict__ k, const float* __restrict__ v,
                            const void* __restrict__ mraw,
                            unsigned short* __restrict__ kp, unsigned short* __restrict__ vp,
                            unsigned* __restrict__ mbits) {
  const int bx = blockIdx.x;
  const int tid = threadIdx.x;

  if (bx < 4096) {
    // ---- K fp32 [B][LK][D] -> Kp frag-packed bf16 ----
    const int gid = bx * 256 + tid;
    const int frag = gid >> 6, lane = gid & 63;
    const int b = frag >> 11;
    const int rem = frag & 2047;
    const int kg = rem >> 5, ks = rem & 31;
    const int key = kg*32 + (lane & 31);
    const int hi = lane >> 5;
    const float* src = k + ((size_t)(b*LKn) + key)*Dn + ks*16 + hi*8;
    const f32x4 a = *(const f32x4*)src;
    const f32x4 c = *(const f32x4*)(src + 4);
    u16x8 o;
#pragma unroll
    for (int j = 0; j < 4; ++j) { o[j] = f2bfu(a[j]); o[j+4] = f2bfu(c[j]); }
    *(u16x8*)(kp + (size_t)frag*512 + lane*8) = o;
    return;
  }

  if (bx < 5120) {
    // ---- V fp32 [B][LK][D] -> Vp frag-packed bf16: [B][kslice][dg][lane][8] ----
    __shared__ float vt[16*512];
    const int bb = bx - 4096;
    const int b = bb >> 7, kslice = bb & 127;
    const float* src = v + ((size_t)(b*LKn) + kslice*16)*Dn;
#pragma unroll
    for (int p = 0; p < 8; ++p) {
      const int idx = p*256 + tid;
      *(f32x4*)&vt[idx*4] = *(const f32x4*)(src + (size_t)idx*4);
    }
    __syncthreads();
    unsigned short* dst = vp + ((size_t)(b*128 + kslice)*16)*512;
#pragma unroll
    for (int p = 0; p < 4; ++p) {
      const int slot = p*256 + tid;
      const int dg = slot >> 6, lane = slot & 63;
      const int d = dg*32 + (lane & 31);
      const int k0 = (lane >> 5)*8;
      u16x8 o;
#pragma unroll
      for (int j = 0; j < 8; ++j) o[j] = f2bfu(vt[(k0+j)*512 + d]);
      *(u16x8*)(dst + (size_t)dg*512 + lane*8) = o;
    }
    return;
  }

  // ---- mask dtype detect + bitmask build (single block): bit=1 <=> masked ----
  __shared__ int sBig, sOff;
  if (tid == 0) { sBig = 0; sOff = 0; }
  __syncthreads();
  const unsigned char* mb = (const unsigned char*)mraw;
  int big = 0, off = 0;
  for (int i = tid; i < Bn*LKn; i += 256) {
    unsigned char vv = mb[i];
    big |= (vv > 1) ? 1 : 0;
    off |= (((i & 3) != 0) && vv != 0) ? 1 : 0;
  }
  if (big) atomicOr(&sBig, 1);
  if (off) atomicOr(&sOff, 1);
  __syncthreads();
  const int f = sBig ? 2 : (sOff ? 1 : 0);
#pragma unroll
  for (int wd = 0; wd < 2; ++wd) {
    const int word = tid*2 + wd;          // 512 u32 words total
    unsigned vv = 0;
#pragma unroll 1
    for (int j = 0; j < 32; ++j) {
      const int i = word*32 + j;
      bool m;
      if (f == 2)      m = ((const float*)mraw)[i] != 0.0f;
      else if (f == 1) m = mb[i] != 0;
      else             m = ((const int*)mraw)[i] != 0;
      vv |= (m ? 1u : 0u) << j;
    }
    mbits[word] = vv;
  }
}

#define BARRIER_LGKM                                        \
  asm volatile("s_waitcnt lgkmcnt(0)" ::: "memory");        \
  __builtin_amdgcn_s_barrier();                             \
  asm volatile("" ::: "memory");

// P buffer geometry (bytes): per-buffer stride 32768, qg stride 16384
#define PBUF 32768
#define PQG  16384

// ---- flash attention: QBLK=64, 8 waves x 32 keys/iter, fixed-base softmax (M=8) ----
// 32-slot unified ring, uniform refill distance 32; mask via SGPR bitmask.
__launch_bounds__(512, 2)
__global__ void attn_kernel(const float* __restrict__ q, const unsigned short* __restrict__ kp,
                            const unsigned short* __restrict__ vp,
                            const float* __restrict__ ratio, const float* __restrict__ scalep,
                            const unsigned* __restrict__ mbp, float* __restrict__ out) {
  __shared__ __align__(16) unsigned short Ql[2*32*512];     // 64 KiB: [qg][ks][hi][qc][8] bf16
  __shared__ __align__(16) unsigned short Pl[2][2*16*512];  // 64 KiB: dbuf x [qg][ks][hi][qc][8]
  __shared__ float redl[8][64];                             // epilogue l reduction

  const int tid = threadIdx.x;
  const int w = tid >> 6, lane = tid & 63;
  const int qc = lane & 31, hi = lane >> 5;
  const int b = blockIdx.x & 7, qtile = blockIdx.x >> 3;   // XCD-affine batches
  const int qbase = qtile * 64;
  const float c2 = scalep[0] * ratio[b] * 1.4426950408889634f;

  // stage Q -> LDS bf16 frag layout [qg][ks][hi][qc][16B]
#pragma unroll
  for (int cc = 0; cc < 8; ++cc) {
    const int idx = cc*512 + tid;
    const int hi2 = idx & 1, qc2 = (idx >> 1) & 31, ks2 = (idx >> 6) & 31, qg2 = idx >> 11;
    const float* src = q + ((size_t)(b*LQn) + qbase + qg2*32 + qc2)*Dn + ks2*16 + hi2*8;
    const f32x4 a = *(const f32x4*)src;
    const f32x4 bb = *(const f32x4*)(src + 4);
    u16x8 o;
#pragma unroll
    for (int j = 0; j < 4; ++j) { o[j] = f2bfu(a[j]); o[j+4] = f2bfu(bb[j]); }
    *(u16x8*)((char*)Ql + qg2*32768 + ks2*1024 + hi2*512 + qc2*16) = o;
  }
  __syncthreads();   // prologue-only full drain

  f32x16 o00, o01, o10, o11;
#pragma unroll
  for (int r = 0; r < 16; ++r) { o00[r]=0.f; o01[r]=0.f; o10[r]=0.f; o11[r]=0.f; }
  float lacc0 = 0.f, lacc1 = 0.f;

  const char* kpB = (const char*)kp + (size_t)b*2048*1024;
  const char* vpB = (const char*)vp + (size_t)b*2048*1024;
  const int loff = lane*16;
  const char* Qlb = (const char*)Ql + hi*512 + qc*16;     // conflict-free frag base
  const char* prc = (const char*)Pl + hi*512 + qc*16;

  // 32-slot unified ring: preload all K frags of iter 0
  bf16x8 pb[32];
  {
    const char* kf0 = kpB + (size_t)w*32768 + loff;
#pragma unroll
    for (int i = 0; i < 32; ++i) pb[i] = *(const bf16x8*)(kf0 + i*1024);
  }

  for (int t = 0; t < NT; ++t) {
    const char* vf  = vpB + ((size_t)(t*256) + w*2)*1024 + loff;
    const char* kfn = kpB + (size_t)(((t+1) & (NT-1))*8 + w)*32768 + loff;  // wraps at t=NT-1
    const unsigned mb32 = mbp[b*64 + t*8 + w];              // uniform -> s_load
    const unsigned mlane = mb32 >> (hi*4);                  // per-lane bit base

    // ---- QK^T: step i consumes K[i], refills V[i] (distance 32) ----
    f32x16 S0, S1;
#pragma unroll
    for (int r = 0; r < 16; ++r) { S0[r] = 0.f; S1[r] = 0.f; }
    __builtin_amdgcn_s_setprio(1);
#pragma unroll
    for (int i = 0; i < 32; ++i) {
      const bf16x8 kk = pb[i];
      const bf16x8 q0 = *(const bf16x8*)(Qlb + i*1024);
      S0 = __builtin_amdgcn_mfma_f32_32x32x16_bf16(kk, q0, S0, 0, 0, 0);
      const bf16x8 q1 = *(const bf16x8*)(Qlb + 32768 + i*1024);
      S1 = __builtin_amdgcn_mfma_f32_32x32x16_bf16(kk, q1, S1, 0, 0, 0);
      pb[i] = *(const bf16x8*)(vf + (size_t)(i >> 1)*16384 + (i & 1)*1024);
    }
    __builtin_amdgcn_s_setprio(0);

    // ---- fixed-base exp (p = masked ? 0 : exp2(S*c2 - 8)) + pack + partial l ----
    float ps0 = 0.f, ps1 = 0.f;
    {
      char* pwr = (char*)Pl + (t & 1)*PBUF + (w*2)*1024 + qc*16 + hi*8;
#pragma unroll
      for (int g = 0; g < 4; ++g) {
        const int off = (g >> 1)*1024 + (g & 1)*512;
        float p0 = ((mlane >> (8*g + 0)) & 1) ? 0.0f : exp2f(fmaf(S0[g*4+0], c2, -8.0f));
        float p1 = ((mlane >> (8*g + 1)) & 1) ? 0.0f : exp2f(fmaf(S0[g*4+1], c2, -8.0f));
        float p2 = ((mlane >> (8*g + 2)) & 1) ? 0.0f : exp2f(fmaf(S0[g*4+2], c2, -8.0f));
        float p3 = ((mlane >> (8*g + 3)) & 1) ? 0.0f : exp2f(fmaf(S0[g*4+3], c2, -8.0f));
        ps0 += (p0 + p1) + (p2 + p3);
        unsigned long long u0 = (unsigned long long)((unsigned int)f2bfu(p0) | ((unsigned int)f2bfu(p1) << 16))
                              | ((unsigned long long)((unsigned int)f2bfu(p2) | ((unsigned int)f2bfu(p3) << 16)) << 32);
        *(unsigned long long*)(pwr + off) = u0;
        p0 = ((mlane >> (8*g + 0)) & 1) ? 0.0f : exp2f(fmaf(S1[g*4+0], c2, -8.0f));
        p1 = ((mlane >> (8*g + 1)) & 1) ? 0.0f : exp2f(fmaf(S1[g*4+1], c2, -8.0f));
        p2 = ((mlane >> (8*g + 2)) & 1) ? 0.0f : exp2f(fmaf(S1[g*4+2], c2, -8.0f));
        p3 = ((mlane >> (8*g + 3)) & 1) ? 0.0f : exp2f(fmaf(S1[g*4+3], c2, -8.0f));
        ps1 += (p0 + p1) + (p2 + p3);
        unsigned long long u1 = (unsigned long long)((unsigned int)f2bfu(p0) | ((unsigned int)f2bfu(p1) << 16))
                              | ((unsigned long long)((unsigned int)f2bfu(p2) | ((unsigned int)f2bfu(p3) << 16)) << 32);
        *(unsigned long long*)(pwr + PQG + off) = u1;
      }
    }
    ps0 += __shfl_xor(ps0, 32);
    ps1 += __shfl_xor(ps1, 32);
    lacc0 += ps0;
    lacc1 += ps1;

    BARRIER_LGKM;   // single barrier: P(t) visible; prior PV reads of this buffer long done

    // ---- PV(t): step j consumes V[j], refills K_next[j] (distance 32) ----
    const char* prd = prc + (t & 1)*PBUF;
    __builtin_amdgcn_s_setprio(1);
#pragma unroll
    for (int ks2 = 0; ks2 < 16; ++ks2) {
      const int j0 = 2*ks2, j1 = 2*ks2 + 1;
      const bf16x8 pf0 = *(const bf16x8*)(prd + ks2*1024);
      const bf16x8 pf1 = *(const bf16x8*)(prd + PQG + ks2*1024);
      const bf16x8 v0 = pb[j0];
      const bf16x8 v1 = pb[j1];
      o00 = __builtin_amdgcn_mfma_f32_32x32x16_bf16(v0, pf0, o00, 0, 0, 0);
      o10 = __builtin_amdgcn_mfma_f32_32x32x16_bf16(v0, pf1, o10, 0, 0, 0);
      o01 = __builtin_amdgcn_mfma_f32_32x32x16_bf16(v1, pf0, o01, 0, 0, 0);
      o11 = __builtin_amdgcn_mfma_f32_32x32x16_bf16(v1, pf1, o11, 0, 0, 0);
      pb[j0] = *(const bf16x8*)(kfn + j0*1024);
      pb[j1] = *(const bf16x8*)(kfn + j1*1024);
    }
    __builtin_amdgcn_s_setprio(0);
  }

  // ---- epilogue: cross-wave l reduction (once), then out = O^T / l ----
  if (lane < 32) { redl[w][qc] = lacc0; redl[w][32 + qc] = lacc1; }
  BARRIER_LGKM;
  float l0 = redl[0][qc], l1 = redl[0][32 + qc];
#pragma unroll
  for (int w2 = 1; w2 < 8; ++w2) { l0 += redl[w2][qc]; l1 += redl[w2][32 + qc]; }

  const float li0 = 1.0f / l0, li1 = 1.0f / l1;
  float* ob0 = out + ((size_t)(b*LQn) + qbase + qc)*Dn + w*64;
  float* ob1 = ob0 + (size_t)32*Dn;
#pragma unroll
  for (int dg = 0; dg < 2; ++dg) {
#pragma unroll
    for (int rq = 0; rq < 4; ++rq) {
      f32x4 ov0, ov1;
#pragma unroll
      for (int c = 0; c < 4; ++c) {
        if (dg == 0) { ov0[c] = o00[rq*4 + c]*li0; ov1[c] = o10[rq*4 + c]*li1; }
        else         { ov0[c] = o01[rq*4 + c]*li0; ov1[c] = o11[rq*4 + c]*li1; }
      }
      *(f32x4*)(ob0 + dg*32 + rq*8 + hi*4) = ov0;
      *(f32x4*)(ob1 + dg*32 + rq*8 + hi*4) = ov1;
    }
  }
}

extern "C" void kernel_launch(void* const* d_in, const int* in_sizes, int n_in,
                              void* d_out, int out_size, void* d_ws, size_t ws_size,
                              hipStream_t stream) {
  const float* q      = (const float*)d_in[0];
  const float* k      = (const float*)d_in[1];
  const float* v      = (const float*)d_in[2];
  const float* ratio  = (const float*)d_in[3];
  const float* scalep = (const float*)d_in[4];
  const void*  mask   = d_in[5];
  float* out = (float*)d_out;
  char* ws = (char*)d_ws;

  if (ws_size < WS_REQ) return;

  unsigned* mbits     = (unsigned*)(ws + WS_MASK_OFF);
  unsigned short* kpk = (unsigned short*)(ws + WS_KP_OFF);
  unsigned short* vpk = (unsigned short*)(ws + WS_VP_OFF);

  hipLaunchKernelGGL(prep_kernel, dim3(5121), dim3(256), 0, stream, k, v, mask, kpk, vpk, mbits);
  hipLaunchKernelGGL(attn_kernel, dim3(Bn*(LQn/64)), dim3(512), 0, stream,
                     q, kpk, vpk, ratio, scalep, mbits, out);
}